// Round 2
// baseline (423.444 us; speedup 1.0000x reference)
//
#include <hip/hip_runtime.h>
#include <cstdint>

#define DIMC 1024
#define NHEAD 16
#define HD 64
#define SEQ 2048
#define NTOK 8192   // B*N = 4*2048

typedef __attribute__((ext_vector_type(8))) short bfrag;   // 8 x bf16 (4 VGPR)
typedef __attribute__((ext_vector_type(4))) short spack4;  // 4 x bf16 (8B)
typedef __attribute__((ext_vector_type(4))) float fv4;

static __device__ __forceinline__ unsigned short f2bf(float f) {
  union { float f; unsigned int u; } v; v.f = f;
  return (unsigned short)((v.u + 0x7fffu + ((v.u >> 16) & 1u)) >> 16);
}

#define MFMA(a, b, c) __builtin_amdgcn_mfma_f32_16x16x32_bf16((a), (b), (c), 0, 0, 0)

// ---------------- x fp32 -> bf16 ----------------
__global__ void cvt_x(const float* __restrict__ x, short* __restrict__ xb) {
  int i = (blockIdx.x * 256 + threadIdx.x) * 4;
  fv4 v = *(const fv4*)&x[i];
  spack4 o;
#pragma unroll
  for (int j = 0; j < 4; ++j) o[j] = (short)f2bf(v[j]);
  *(spack4*)&xb[i] = o;
}

// ---------------- W [R][C] fp32 -> WT [C][R] bf16 ----------------
__global__ void transpose_w(const float* __restrict__ W, short* __restrict__ WT,
                            int R, int C) {
  __shared__ float tile[32][33];
  const int t = threadIdx.x;
  const int r = t >> 3, c4 = t & 7;
  const int r0 = blockIdx.y * 32, c0 = blockIdx.x * 32;
  fv4 v = *(const fv4*)&W[(size_t)(r0 + r) * C + c0 + c4 * 4];
#pragma unroll
  for (int j = 0; j < 4; ++j) tile[r][c4 * 4 + j] = v[j];
  __syncthreads();
  spack4 o;
#pragma unroll
  for (int j = 0; j < 4; ++j) o[j] = (short)f2bf(tile[c4 * 4 + j][r]);
  *(spack4*)&WT[(size_t)(c0 + r) * R + r0 + c4 * 4] = o;
}

// ---------------- GEMM: C[M][N] = A[M][K] * BT[N][K]^T + bias ----------------
// MODE 0: qkv epilogue (scatter Q scaled, K, V^T as bf16)
// MODE 1: proj epilogue (fp32 out + bias)
template <int MODE>
__launch_bounds__(256)
__global__ void gemm_bt(const short* __restrict__ A, const short* __restrict__ BT,
                        const float* __restrict__ bias, int M, int N, int K,
                        short* __restrict__ out0, short* __restrict__ out1,
                        short* __restrict__ out2, float* __restrict__ outf) {
  __shared__ alignas(16) char As[128 * 128];  // 128 rows x 64 bf16 (swizzled)
  __shared__ alignas(16) char Bs[128 * 128];
  const int t = threadIdx.x;
  const int lane = t & 63;
  const int wid = t >> 6;
  const int wm = wid >> 1, wn = wid & 1;
  const int g = lane >> 4, l15 = lane & 15;
  const int row0 = blockIdx.y * 128;
  const int col0 = blockIdx.x * 128;
  const int lr = t >> 3, ls = t & 7;

  fv4 acc[4][4] = {};

  for (int k0 = 0; k0 < K; k0 += 64) {
    bfrag av[4], bv[4];
#pragma unroll
    for (int i = 0; i < 4; ++i) {
      int row = lr + i * 32;
      av[i] = *(const bfrag*)&A[(size_t)(row0 + row) * K + k0 + ls * 8];
      bv[i] = *(const bfrag*)&BT[(size_t)(col0 + row) * K + k0 + ls * 8];
    }
    __syncthreads();
#pragma unroll
    for (int i = 0; i < 4; ++i) {
      int row = lr + i * 32;
      int kb = (ls * 16) ^ ((row & 7) << 4);
      *(bfrag*)&As[row * 128 + kb] = av[i];
      *(bfrag*)&Bs[row * 128 + kb] = bv[i];
    }
    __syncthreads();
#pragma unroll
    for (int kk = 0; kk < 2; ++kk) {
      bfrag af[4], bf[4];
#pragma unroll
      for (int mm = 0; mm < 4; ++mm) {
        int row = wm * 64 + mm * 16 + l15;
        af[mm] = *(const bfrag*)&As[row * 128 + ((kk * 64 + g * 16) ^ ((row & 7) << 4))];
      }
#pragma unroll
      for (int nn = 0; nn < 4; ++nn) {
        int row = wn * 64 + nn * 16 + l15;
        bf[nn] = *(const bfrag*)&Bs[row * 128 + ((kk * 64 + g * 16) ^ ((row & 7) << 4))];
      }
#pragma unroll
      for (int mm = 0; mm < 4; ++mm)
#pragma unroll
        for (int nn = 0; nn < 4; ++nn)
          acc[mm][nn] = MFMA(af[mm], bf[nn], acc[mm][nn]);
    }
  }

  if (MODE == 0) {
    const float qs = 0.125f * 1.4426950408889634f;  // head_dim^-0.5 * log2(e)
#pragma unroll
    for (int nn = 0; nn < 4; ++nn) {
      int col = col0 + wn * 64 + nn * 16 + l15;
      int which = col >> 10;
      int rem = col & 1023;
      int h = rem >> 6, d = rem & 63;
      float bval = bias[col];
#pragma unroll
      for (int mm = 0; mm < 4; ++mm) {
        int tok = row0 + wm * 64 + mm * 16 + g * 4;  // token row (4 consecutive)
        int b = tok >> 11, n = tok & 2047;
        int bh = b * NHEAD + h;
        if (which == 0) {
#pragma unroll
          for (int r = 0; r < 4; ++r)
            out0[((size_t)bh * SEQ + n + r) * HD + d] =
                (short)f2bf((acc[mm][nn][r] + bval) * qs);
        } else if (which == 1) {
#pragma unroll
          for (int r = 0; r < 4; ++r)
            out1[((size_t)bh * SEQ + n + r) * HD + d] =
                (short)f2bf(acc[mm][nn][r] + bval);
        } else {
          spack4 p;
#pragma unroll
          for (int r = 0; r < 4; ++r) p[r] = (short)f2bf(acc[mm][nn][r] + bval);
          *(spack4*)&out2[((size_t)bh * HD + d) * SEQ + n] = p;
        }
      }
    }
  } else {
#pragma unroll
    for (int nn = 0; nn < 4; ++nn) {
      int col = col0 + wn * 64 + nn * 16 + l15;
      float bval = bias[col];
#pragma unroll
      for (int mm = 0; mm < 4; ++mm) {
        int tok = row0 + wm * 64 + mm * 16 + g * 4;
#pragma unroll
        for (int r = 0; r < 4; ++r)
          outf[(size_t)(tok + r) * N + col] = acc[mm][nn][r] + bval;
      }
    }
  }
}

// ---------------- flash attention ----------------
// Q [BH][SEQ][HD] bf16 (pre-scaled by 0.125*log2e), K [BH][SEQ][HD], VT [BH][HD][SEQ]
// O bf16 [NTOK][DIMC]
__launch_bounds__(256)
__global__ void attn_fwd(const short* __restrict__ Q, const short* __restrict__ Kb,
                         const short* __restrict__ VT, short* __restrict__ O) {
  __shared__ alignas(16) char Ks[32 * 128];      // [32 keys][64 d] swizzled
  __shared__ alignas(16) char Vs[64 * 80];       // [64 d][32 k + pad]
  __shared__ alignas(16) char Ps[4][16 * 80];    // per-wave [16 q][32 k + pad]

  const int t = threadIdx.x, lane = t & 63, wid = t >> 6;
  const int g = lane >> 4, l15 = lane & 15;
  const int bh = blockIdx.y;
  const size_t base = (size_t)bh * SEQ * HD;
  const short* Qp = Q + base;
  const short* Kp = Kb + base;
  const short* Vp = VT + base;   // [HD][SEQ]
  const int q0 = blockIdx.x * 64 + wid * 16;

  bfrag qf[2];
#pragma unroll
  for (int kk = 0; kk < 2; ++kk)
    qf[kk] = *(const bfrag*)&Qp[(q0 + l15) * HD + kk * 32 + g * 8];

  fv4 oa[4] = {};
  float m[4], l[4];
#pragma unroll
  for (int r = 0; r < 4; ++r) { m[r] = -1e30f; l[r] = 0.f; }

  const int kr = t >> 3, ks = t & 7;  // K staging: 32 rows x 8 slots
  const int vr = t >> 2, vs = t & 3;  // V staging: 64 rows x 4 slots

  for (int kt = 0; kt < SEQ / 32; ++kt) {
    bfrag kv = *(const bfrag*)&Kp[(kt * 32 + kr) * HD + ks * 8];
    bfrag vv = *(const bfrag*)&Vp[(size_t)vr * SEQ + kt * 32 + vs * 8];
    __syncthreads();
    *(bfrag*)&Ks[kr * 128 + ((ks * 16) ^ ((kr & 7) << 4))] = kv;
    *(bfrag*)&Vs[vr * 80 + vs * 16] = vv;
    __syncthreads();

    // S = Q K^T : C-frag col=key(l15), row=q(4g+r)
    fv4 s0 = {}, s1 = {};
#pragma unroll
    for (int kk = 0; kk < 2; ++kk) {
      int kb = kk * 64 + g * 16;
      bfrag b0 = *(const bfrag*)&Ks[l15 * 128 + (kb ^ ((l15 & 7) << 4))];
      int r1 = 16 + l15;
      bfrag b1 = *(const bfrag*)&Ks[r1 * 128 + (kb ^ ((r1 & 7) << 4))];
      s0 = MFMA(qf[kk], b0, s0);
      s1 = MFMA(qf[kk], b1, s1);
    }

    // online softmax (exp2 domain; Q was pre-scaled by 0.125*log2e)
    float corr[4];
#pragma unroll
    for (int r = 0; r < 4; ++r) {
      float v = fmaxf(s0[r], s1[r]);
      v = fmaxf(v, __shfl_xor(v, 1));
      v = fmaxf(v, __shfl_xor(v, 2));
      v = fmaxf(v, __shfl_xor(v, 4));
      v = fmaxf(v, __shfl_xor(v, 8));
      float mn = fmaxf(m[r], v);
      corr[r] = exp2f(m[r] - mn);
      m[r] = mn;
    }
    float p0[4], p1[4];
#pragma unroll
    for (int r = 0; r < 4; ++r) {
      p0[r] = exp2f(s0[r] - m[r]);
      p1[r] = exp2f(s1[r] - m[r]);
      float v = p0[r] + p1[r];
      v += __shfl_xor(v, 1);
      v += __shfl_xor(v, 2);
      v += __shfl_xor(v, 4);
      v += __shfl_xor(v, 8);
      l[r] = l[r] * corr[r] + v;
    }
#pragma unroll
    for (int nn = 0; nn < 4; ++nn)
#pragma unroll
      for (int r = 0; r < 4; ++r) oa[nn][r] *= corr[r];

    // P (C-frag layout) -> LDS -> A-frag layout
    char* pp = &Ps[wid][0];
#pragma unroll
    for (int r = 0; r < 4; ++r) {
      int qrow = g * 4 + r;
      *(short*)&pp[qrow * 80 + l15 * 2] = (short)f2bf(p0[r]);
      *(short*)&pp[qrow * 80 + 32 + l15 * 2] = (short)f2bf(p1[r]);
    }
    bfrag pa = *(const bfrag*)&pp[l15 * 80 + g * 16];
#pragma unroll
    for (int nn = 0; nn < 4; ++nn) {
      int d = nn * 16 + l15;
      bfrag vb = *(const bfrag*)&Vs[d * 80 + g * 16];
      oa[nn] = MFMA(pa, vb, oa[nn]);
    }
  }

  const int b = bh >> 4, h = bh & 15;
#pragma unroll
  for (int nn = 0; nn < 4; ++nn) {
    int d = nn * 16 + l15;
#pragma unroll
    for (int r = 0; r < 4; ++r) {
      int q = q0 + g * 4 + r;
      float v = oa[nn][r] / l[r];
      O[((size_t)b * SEQ + q) * DIMC + h * HD + d] = (short)f2bf(v);
    }
  }
}

extern "C" void kernel_launch(void* const* d_in, const int* in_sizes, int n_in,
                              void* d_out, int out_size, void* d_ws, size_t ws_size,
                              hipStream_t stream) {
  const float* x     = (const float*)d_in[0];
  const float* Wqkv  = (const float*)d_in[1];
  const float* bqkv  = (const float*)d_in[2];
  const float* Wproj = (const float*)d_in[3];
  const float* bproj = (const float*)d_in[4];
  float* out = (float*)d_out;
  char* ws = (char*)d_ws;

  short* xb  = (short*)(ws);                 // 16.8 MB  x bf16 [8192][1024]
  short* WqT = (short*)(ws + 16777216);      //  6.3 MB  Wqkv^T bf16 [3072][1024]
  short* WpT = (short*)(ws + 23068672);      //  2.1 MB  Wproj^T bf16 [1024][1024]
  short* Qb  = (short*)(ws + 25165824);      // 16.8 MB  [64][2048][64]
  short* Kb  = (short*)(ws + 41943040);      // 16.8 MB
  short* VTb = (short*)(ws + 58720256);      // 16.8 MB  [64][64][2048]
  short* Ob  = (short*)(ws + 75497472);      // 16.8 MB  [8192][1024]

  cvt_x<<<8192, 256, 0, stream>>>(x, xb);
  transpose_w<<<dim3(96, 32), 256, 0, stream>>>(Wqkv, WqT, 1024, 3072);
  transpose_w<<<dim3(32, 32), 256, 0, stream>>>(Wproj, WpT, 1024, 1024);
  gemm_bt<0><<<dim3(24, 64), 256, 0, stream>>>(xb, WqT, bqkv, NTOK, 3072, 1024,
                                               Qb, Kb, VTb, nullptr);
  attn_fwd<<<dim3(32, 64), 256, 0, stream>>>(Qb, Kb, VTb, Ob);
  gemm_bt<1><<<dim3(8, 64), 256, 0, stream>>>(Ob, WpT, bproj, NTOK, 1024, 1024,
                                              nullptr, nullptr, nullptr, out);
}

// Round 7
// 228.815 us; speedup vs baseline: 1.8506x; 1.8506x over previous
//
#include <hip/hip_runtime.h>
#include <cstdint>

#define DIMC 1024
#define NHEAD 16
#define HD 64
#define SEQ 2048
#define NTOK 8192   // B*N = 4*2048

typedef __attribute__((ext_vector_type(8))) short bfrag;   // 8 x bf16 (4 VGPR)
typedef __attribute__((ext_vector_type(4))) short spack4;  // 4 x bf16 (8B)
typedef __attribute__((ext_vector_type(4))) float fv4;
typedef __attribute__((ext_vector_type(16))) float f32x16;
typedef __attribute__((ext_vector_type(4))) int iv4;

static __device__ __forceinline__ unsigned short f2bf(float f) {
  union { float f; unsigned int u; } v; v.f = f;
  return (unsigned short)((v.u + 0x7fffu + ((v.u >> 16) & 1u)) >> 16);
}
static __device__ __forceinline__ unsigned int pack2(float a, float b) {
  return (unsigned int)f2bf(a) | ((unsigned int)f2bf(b) << 16);
}

#define MFMA(a, b, c) __builtin_amdgcn_mfma_f32_16x16x32_bf16((a), (b), (c), 0, 0, 0)
#define MFMA32(a, b, c) __builtin_amdgcn_mfma_f32_32x32x16_bf16((a), (b), (c), 0, 0, 0)

// ---------------- x fp32 -> bf16 ----------------
__global__ void cvt_x(const float* __restrict__ x, short* __restrict__ xb) {
  int i = (blockIdx.x * 256 + threadIdx.x) * 4;
  fv4 v = *(const fv4*)&x[i];
  spack4 o;
#pragma unroll
  for (int j = 0; j < 4; ++j) o[j] = (short)f2bf(v[j]);
  *(spack4*)&xb[i] = o;
}

// ---------------- W [R][C] fp32 -> WT [C][R] bf16 ----------------
__global__ void transpose_w(const float* __restrict__ W, short* __restrict__ WT,
                            int R, int C) {
  __shared__ float tile[32][33];
  const int t = threadIdx.x;
  const int r = t >> 3, c4 = t & 7;
  const int r0 = blockIdx.y * 32, c0 = blockIdx.x * 32;
  fv4 v = *(const fv4*)&W[(size_t)(r0 + r) * C + c0 + c4 * 4];
#pragma unroll
  for (int j = 0; j < 4; ++j) tile[r][c4 * 4 + j] = v[j];
  __syncthreads();
  spack4 o;
#pragma unroll
  for (int j = 0; j < 4; ++j) o[j] = (short)f2bf(tile[c4 * 4 + j][r]);
  *(spack4*)&WT[(size_t)(c0 + r) * R + r0 + c4 * 4] = o;
}

// ---------------- GEMM: C[M][N] = A[M][K] * BT[N][K]^T + bias ----------------
template <int MODE>
__launch_bounds__(256)
__global__ void gemm_bt(const short* __restrict__ A, const short* __restrict__ BT,
                        const float* __restrict__ bias, int M, int N, int K,
                        short* __restrict__ out0, short* __restrict__ out1,
                        short* __restrict__ out2, float* __restrict__ outf) {
  __shared__ alignas(16) char As[128 * 128];
  __shared__ alignas(16) char Bs[128 * 128];
  const int t = threadIdx.x;
  const int lane = t & 63;
  const int wid = t >> 6;
  const int wm = wid >> 1, wn = wid & 1;
  const int g = lane >> 4, l15 = lane & 15;
  const int row0 = blockIdx.y * 128;
  const int col0 = blockIdx.x * 128;
  const int lr = t >> 3, ls = t & 7;

  fv4 acc[4][4] = {};

  for (int k0 = 0; k0 < K; k0 += 64) {
    bfrag av[4], bv[4];
#pragma unroll
    for (int i = 0; i < 4; ++i) {
      int row = lr + i * 32;
      av[i] = *(const bfrag*)&A[(size_t)(row0 + row) * K + k0 + ls * 8];
      bv[i] = *(const bfrag*)&BT[(size_t)(col0 + row) * K + k0 + ls * 8];
    }
    __syncthreads();
#pragma unroll
    for (int i = 0; i < 4; ++i) {
      int row = lr + i * 32;
      int kb = (ls * 16) ^ ((row & 7) << 4);
      *(bfrag*)&As[row * 128 + kb] = av[i];
      *(bfrag*)&Bs[row * 128 + kb] = bv[i];
    }
    __syncthreads();
#pragma unroll
    for (int kk = 0; kk < 2; ++kk) {
      bfrag af[4], bf[4];
#pragma unroll
      for (int mm = 0; mm < 4; ++mm) {
        int row = wm * 64 + mm * 16 + l15;
        af[mm] = *(const bfrag*)&As[row * 128 + ((kk * 64 + g * 16) ^ ((row & 7) << 4))];
      }
#pragma unroll
      for (int nn = 0; nn < 4; ++nn) {
        int row = wn * 64 + nn * 16 + l15;
        bf[nn] = *(const bfrag*)&Bs[row * 128 + ((kk * 64 + g * 16) ^ ((row & 7) << 4))];
      }
#pragma unroll
      for (int mm = 0; mm < 4; ++mm)
#pragma unroll
        for (int nn = 0; nn < 4; ++nn)
          acc[mm][nn] = MFMA(af[mm], bf[nn], acc[mm][nn]);
    }
  }

  if (MODE == 0) {
    const float qs = 0.125f * 1.4426950408889634f;  // head_dim^-0.5 * log2(e)
#pragma unroll
    for (int nn = 0; nn < 4; ++nn) {
      int col = col0 + wn * 64 + nn * 16 + l15;
      int which = col >> 10;
      int rem = col & 1023;
      int h = rem >> 6, d = rem & 63;
      float bval = bias[col];
#pragma unroll
      for (int mm = 0; mm < 4; ++mm) {
        int tok = row0 + wm * 64 + mm * 16 + g * 4;
        int b = tok >> 11, n = tok & 2047;
        int bh = b * NHEAD + h;
        if (which == 0) {
#pragma unroll
          for (int r = 0; r < 4; ++r)
            out0[((size_t)bh * SEQ + n + r) * HD + d] =
                (short)f2bf((acc[mm][nn][r] + bval) * qs);
        } else if (which == 1) {
#pragma unroll
          for (int r = 0; r < 4; ++r)
            out1[((size_t)bh * SEQ + n + r) * HD + d] =
                (short)f2bf(acc[mm][nn][r] + bval);
        } else {
          spack4 p;
#pragma unroll
          for (int r = 0; r < 4; ++r) p[r] = (short)f2bf(acc[mm][nn][r] + bval);
          *(spack4*)&out2[((size_t)bh * HD + d) * SEQ + n] = p;
        }
      }
    }
  } else {
#pragma unroll
    for (int nn = 0; nn < 4; ++nn) {
      int col = col0 + wn * 64 + nn * 16 + l15;
      float bval = bias[col];
#pragma unroll
      for (int mm = 0; mm < 4; ++mm) {
        int tok = row0 + wm * 64 + mm * 16 + g * 4;
#pragma unroll
        for (int r = 0; r < 4; ++r)
          outf[(size_t)(tok + r) * N + col] = acc[mm][nn][r] + bval;
      }
    }
  }
}

// ---------------- flash attention, swapped-QK 32x32 in-register softmax ------
// Q [BH][SEQ][HD] bf16 (pre-scaled by 0.125*log2e), K [BH][SEQ][HD],
// VT [BH][HD][SEQ].  O bf16 [NTOK][DIMC].
// Per wave: 32 q-rows. S^T = mfma32(K, Q): C col = q = lane&31,
// C row = key = (r&3)+8*(r>>2)+4*hi. O^T = mfma32(V^T, P^T): col = q again,
// row = d. Softmax state (m, l) is per-lane (its q) -> rescale is in-lane.
// BISECTION ROUND: cvt_pk-asm and permlane32_swap replaced by f2bf packing +
// __shfl_xor(32) + hi-select (round-2-verified primitives, unambiguous
// semantics). Everything else identical to round 5.
__launch_bounds__(256, 3)
__global__ void attn_fwd(const short* __restrict__ Q, const short* __restrict__ Kb,
                         const short* __restrict__ VT, short* __restrict__ O) {
  __shared__ alignas(16) char Ks[2][8192];   // [64 keys][64 d] bf16, XOR-swizzled
  __shared__ alignas(16) char Vs[2][8192];   // [64 d][64 keys] bf16, XOR-swizzled

  const int t = threadIdx.x, lane = t & 63, wid = t >> 6;
  const int l31 = lane & 31, hi = lane >> 5, l7 = lane & 7;

  // XCD swizzle: all 16 q-tiles of one bh land on one XCD (K/V L2-resident).
  const int bid = blockIdx.x;
  const int xcd = bid & 7, mm_ = bid >> 3;
  const int bh = xcd + 8 * (mm_ >> 4);
  const int qt = mm_ & 15;

  const size_t base = (size_t)bh * SEQ * HD;
  const short* Qp = Q + base;
  const short* Kp = Kb + base;
  const short* Vp = VT + base;   // [HD][SEQ]
  const int q0 = qt * 128 + wid * 32;

  // Q as B-frag: col = q = lane&31, k(d) = dblk*16 + hi*8 + j
  bfrag qf[4];
#pragma unroll
  for (int dblk = 0; dblk < 4; ++dblk)
    qf[dblk] = *(const bfrag*)&Qp[(size_t)(q0 + l31) * HD + dblk * 16 + hi * 8];

  f32x16 oacc[2] = {};          // O^T: [dh] rows d = dh*32+(r&3)+8*(r>>2)+4*hi
  float m = -1e30f, l = 0.f;

  // staging: 256 threads x 2 chunks of 16B per tile per matrix
  const int sr = t >> 3, ss = t & 7;
  const int swz0 = (ss * 16) ^ ((sr & 7) << 4);   // same for row sr+32

  { // prologue: stage tile 0
    bfrag k0 = *(const bfrag*)&Kp[(size_t)sr * HD + ss * 8];
    bfrag k1 = *(const bfrag*)&Kp[(size_t)(32 + sr) * HD + ss * 8];
    bfrag v0 = *(const bfrag*)&Vp[(size_t)sr * SEQ + ss * 8];
    bfrag v1 = *(const bfrag*)&Vp[(size_t)(sr + 32) * SEQ + ss * 8];
    *(bfrag*)&Ks[0][sr * 128 + swz0] = k0;
    *(bfrag*)&Ks[0][(sr + 32) * 128 + swz0] = k1;
    *(bfrag*)&Vs[0][sr * 128 + swz0] = v0;
    *(bfrag*)&Vs[0][(sr + 32) * 128 + swz0] = v1;
  }
  __syncthreads();

  int cur = 0;
  for (int kt = 0; kt < SEQ / 64; ++kt) {
    bfrag nk0, nk1, nv0, nv1;
    const bool pre = (kt + 1) < (SEQ / 64);
    if (pre) {  // issue next-tile global loads early (T14)
      const int kb2 = (kt + 1) * 64;
      nk0 = *(const bfrag*)&Kp[(size_t)(kb2 + sr) * HD + ss * 8];
      nk1 = *(const bfrag*)&Kp[(size_t)(kb2 + 32 + sr) * HD + ss * 8];
      nv0 = *(const bfrag*)&Vp[(size_t)sr * SEQ + kb2 + ss * 8];
      nv1 = *(const bfrag*)&Vp[(size_t)(sr + 32) * SEQ + kb2 + ss * 8];
    }

    const char* Kc = Ks[cur];
    const char* Vc = Vs[cur];

    // S^T = K · Q^T  (two 32-key C-frags, contraction over d=64 in 4 steps)
    f32x16 sf[2] = {};
#pragma unroll
    for (int kb = 0; kb < 2; ++kb) {
#pragma unroll
      for (int dblk = 0; dblk < 4; ++dblk) {
        const int row = kb * 32 + l31;
        bfrag kf = *(const bfrag*)&Kc[row * 128 + ((dblk * 32 + hi * 16) ^ (l7 << 4))];
        sf[kb] = MFMA32(kf, qf[dblk], sf[kb]);
      }
    }

    // in-register softmax over 64 keys (lane + its hi-partner via shfl_xor 32)
    float pm = sf[0][0];
#pragma unroll
    for (int i = 1; i < 16; ++i) pm = fmaxf(pm, sf[0][i]);
#pragma unroll
    for (int i = 0; i < 16; ++i) pm = fmaxf(pm, sf[1][i]);
    pm = fmaxf(pm, __shfl_xor(pm, 32));

    // exact-max rescale (every tile)
    {
      const float mn = fmaxf(m, pm);
      const float corr = __builtin_amdgcn_exp2f(m - mn);
      m = mn;
      l *= corr;
#pragma unroll
      for (int dh = 0; dh < 2; ++dh)
#pragma unroll
        for (int i = 0; i < 16; ++i) oacc[dh][i] *= corr;
    }

    float sum = 0.f;
#pragma unroll
    for (int kb = 0; kb < 2; ++kb)
#pragma unroll
      for (int i = 0; i < 16; ++i) {
        const float e = __builtin_amdgcn_exp2f(sf[kb][i] - m);
        sf[kb][i] = e;                    // reuse sf as P storage
        sum += e;
      }
    l += sum + __shfl_xor(sum, 32);

    // P -> bf16 B-frag. Lane holds (within 16-key block s of hb):
    //   x01={s+4hi+0,1} x23={s+4hi+2,3} y45={s+8+4hi+0,1} y67={s+8+4hi+2,3}
    // B-frag word w needs keys s + hi*8 + {2w, 2w+1}:
    //   hi=0: w0=x01 w1=x23 w2=partner(x01) w3=partner(x23)
    //   hi=1: w0=partner(y45) w1=partner(y67) w2=y45 w3=y67
#pragma unroll
    for (int hb = 0; hb < 4; ++hb) {
      const int kb = hb >> 1, ob = (hb & 1) * 8;
      const unsigned int x01 = pack2(sf[kb][ob + 0], sf[kb][ob + 1]);
      const unsigned int x23 = pack2(sf[kb][ob + 2], sf[kb][ob + 3]);
      const unsigned int y45 = pack2(sf[kb][ob + 4], sf[kb][ob + 5]);
      const unsigned int y67 = pack2(sf[kb][ob + 6], sf[kb][ob + 7]);
      const unsigned int px01 = (unsigned int)__shfl_xor((int)x01, 32);
      const unsigned int px23 = (unsigned int)__shfl_xor((int)x23, 32);
      const unsigned int py45 = (unsigned int)__shfl_xor((int)y45, 32);
      const unsigned int py67 = (unsigned int)__shfl_xor((int)y67, 32);
      iv4 pw;
      pw[0] = (int)(hi ? py45 : x01);
      pw[1] = (int)(hi ? py67 : x23);
      pw[2] = (int)(hi ? y45 : px01);
      pw[3] = (int)(hi ? y67 : px23);
      const bfrag pb = __builtin_bit_cast(bfrag, pw);
#pragma unroll
      for (int dh = 0; dh < 2; ++dh) {
        const int row = dh * 32 + l31;
        bfrag vf = *(const bfrag*)&Vc[row * 128 + ((hb * 32 + hi * 16) ^ (l7 << 4))];
        oacc[dh] = MFMA32(vf, pb, oacc[dh]);
      }
    }

    if (pre) {
      const int nb = cur ^ 1;
      *(bfrag*)&Ks[nb][sr * 128 + swz0] = nk0;
      *(bfrag*)&Ks[nb][(sr + 32) * 128 + swz0] = nk1;
      *(bfrag*)&Vs[nb][sr * 128 + swz0] = nv0;
      *(bfrag*)&Vs[nb][(sr + 32) * 128 + swz0] = nv1;
      __syncthreads();
    }
    cur ^= 1;
  }

  // epilogue: O = O^T / l
  const float inv = 1.0f / l;
  const int b = bh >> 4, h = bh & 15;
  const int q = q0 + l31;
#pragma unroll
  for (int dh = 0; dh < 2; ++dh)
#pragma unroll
    for (int gp = 0; gp < 4; ++gp) {
      const int d0 = dh * 32 + gp * 8 + hi * 4;
      spack4 pk;
#pragma unroll
      for (int j = 0; j < 4; ++j)
        pk[j] = (short)f2bf(oacc[dh][gp * 4 + j] * inv);
      *(spack4*)&O[((size_t)b * SEQ + q) * DIMC + h * HD + d0] = pk;
    }
}

extern "C" void kernel_launch(void* const* d_in, const int* in_sizes, int n_in,
                              void* d_out, int out_size, void* d_ws, size_t ws_size,
                              hipStream_t stream) {
  const float* x     = (const float*)d_in[0];
  const float* Wqkv  = (const float*)d_in[1];
  const float* bqkv  = (const float*)d_in[2];
  const float* Wproj = (const float*)d_in[3];
  const float* bproj = (const float*)d_in[4];
  float* out = (float*)d_out;
  char* ws = (char*)d_ws;

  short* xb  = (short*)(ws);                 // 16.8 MB  x bf16 [8192][1024]
  short* WqT = (short*)(ws + 16777216);      //  6.3 MB  Wqkv^T bf16 [3072][1024]
  short* WpT = (short*)(ws + 23068672);      //  2.1 MB  Wproj^T bf16 [1024][1024]
  short* Qb  = (short*)(ws + 25165824);      // 16.8 MB  [64][2048][64]
  short* Kb  = (short*)(ws + 41943040);      // 16.8 MB
  short* VTb = (short*)(ws + 58720256);      // 16.8 MB  [64][64][2048]
  short* Ob  = (short*)(ws + 75497472);      // 16.8 MB  [8192][1024]

  cvt_x<<<8192, 256, 0, stream>>>(x, xb);
  transpose_w<<<dim3(96, 32), 256, 0, stream>>>(Wqkv, WqT, 1024, 3072);
  transpose_w<<<dim3(32, 32), 256, 0, stream>>>(Wproj, WpT, 1024, 1024);
  gemm_bt<0><<<dim3(24, 64), 256, 0, stream>>>(xb, WqT, bqkv, NTOK, 3072, 1024,
                                               Qb, Kb, VTb, nullptr);
  attn_fwd<<<1024, 256, 0, stream>>>(Qb, Kb, VTb, Ob);
  gemm_bt<1><<<dim3(8, 64), 256, 0, stream>>>(Ob, WpT, bproj, NTOK, 1024, 1024,
                                              nullptr, nullptr, nullptr, out);
}